// Round 19
// baseline (88.295 us; speedup 1.0000x reference)
//
#include <hip/hip_runtime.h>
#include <stdint.h>

#define BB 16
#define NN 1024
#define DD 64
#define CC 64
#define KMAX 20
#define ROWS 8

typedef unsigned long long u64;
typedef float f32x2 __attribute__((ext_vector_type(2)));
typedef float f32x4v __attribute__((ext_vector_type(4)));
typedef short bf16x8 __attribute__((ext_vector_type(8)));

__device__ inline u64 umin64(u64 a, u64 b) { return a < b ? a : b; }

__device__ inline unsigned f2bf(float f) {        // fp32 -> bf16 bits, RNE
    unsigned u = __float_as_uint(f);
    return (u + 0x7FFFu + ((u >> 16) & 1u)) >> 16;
}

__device__ inline bf16x8 pack8(const float4 a, const float4 b) {
    union { unsigned u[4]; bf16x8 v; } r;
    r.u[0] = f2bf(a.x) | (f2bf(a.y) << 16);
    r.u[1] = f2bf(a.z) | (f2bf(a.w) << 16);
    r.u[2] = f2bf(b.x) | (f2bf(b.y) << 16);
    r.u[3] = f2bf(b.z) | (f2bf(b.w) << 16);
    return r.v;
}

struct bfpair { bf16x8 hi, lo; };
__device__ __forceinline__ bfpair split8(const float v[8]) {
    union { unsigned u[4]; bf16x8 x; } H, L;
#pragma unroll
    for (int i = 0; i < 4; ++i) {
        unsigned h0 = f2bf(v[2 * i]), h1 = f2bf(v[2 * i + 1]);
        float r0 = v[2 * i] - __uint_as_float(h0 << 16);
        float r1 = v[2 * i + 1] - __uint_as_float(h1 << 16);
        H.u[i] = h0 | (h1 << 16);
        L.u[i] = f2bf(r0) | (f2bf(r1) << 16);
    }
    bfpair r; r.hi = H.x; r.lo = L.x; return r;
}

// GroupNorm on one group of 4 channels (lane-local), + gamma/beta + ReLU
__device__ inline void gn4(float4& h, const float4 g, const float4 be) {
    float mu = (h.x + h.y + h.z + h.w) * 0.25f;
    float dx = h.x - mu, dy = h.y - mu, dz = h.z - mu, dw = h.w - mu;
    float var = (dx * dx + dy * dy + dz * dz + dw * dw) * 0.25f;
    float rs = __builtin_amdgcn_rsqf(var + 1e-5f);
    h.x = fmaxf(fmaf(dx * rs, g.x, be.x), 0.f);
    h.y = fmaxf(fmaf(dy * rs, g.y, be.y), 0.f);
    h.z = fmaxf(fmaf(dz * rs, g.z, be.z), 0.f);
    h.w = fmaxf(fmaf(dw * rs, g.w, be.w), 0.f);
}

// ---------------- K1 fused producers (grid-partitioned, one dispatch) ----------------
// blocks [0,1024):   k1a body — split-bf16 MFMA feats (base, fb)
// blocks [1024,2048): k1b body — xT + x2 (bit-frozen)
// block 2048:         k0 body  — counts + keff (256-thread variant, R10/R11-proven)
__global__ __launch_bounds__(256) void k1_fused(const float* __restrict__ x,
                                                const float* __restrict__ W1,
                                                const float* __restrict__ b1,
                                                float* __restrict__ base,
                                                float* __restrict__ fb,
                                                float* __restrict__ xT,
                                                float* __restrict__ x2,
                                                const void* __restrict__ maskp,
                                                int* __restrict__ counts,
                                                int* __restrict__ keff) {
    __shared__ float sX[16][65];
    __shared__ int scnt[BB];
    int bid = blockIdx.x;
    int w = threadIdx.x >> 6, lane = threadIdx.x & 63;

    if (bid < 1024) {
        // ---- k1a: feats (bit-identical to R18 k1a) ----
        int lg = lane >> 4, lr = lane & 15;
        int p0 = bid * 16;
        float av[8];
        bfpair A[2];
        {
            const float* xr = x + (size_t)(p0 + lr) * DD;
#pragma unroll
            for (int kt = 0; kt < 2; ++kt) {
                float4 a0 = *(const float4*)(xr + kt * 32 + lg * 8);
                float4 a1 = *(const float4*)(xr + kt * 32 + lg * 8 + 4);
                av[0] = a0.x; av[1] = a0.y; av[2] = a0.z; av[3] = a0.w;
                av[4] = a1.x; av[5] = a1.y; av[6] = a1.z; av[7] = a1.w;
                A[kt] = split8(av);
            }
        }
        bfpair Wa[2], Wb[2];
#pragma unroll
        for (int kt = 0; kt < 2; ++kt) {
            const float* wpa = W1 + (size_t)(kt * 32 + lg * 8) * CC + w * 16 + lr;
            float wv[8];
#pragma unroll
            for (int e = 0; e < 8; ++e) wv[e] = wpa[e * CC];
            Wa[kt] = split8(wv);
            const float* wpb = wpa + (size_t)DD * CC;
#pragma unroll
            for (int e = 0; e < 8; ++e) wv[e] = wpb[e * CC];
            Wb[kt] = split8(wv);
        }
        f32x4v P = {0, 0, 0, 0}, Q = {0, 0, 0, 0};
#pragma unroll
        for (int kt = 0; kt < 2; ++kt) {
            P = __builtin_amdgcn_mfma_f32_16x16x32_bf16(A[kt].hi, Wa[kt].hi, P, 0, 0, 0);
            P = __builtin_amdgcn_mfma_f32_16x16x32_bf16(A[kt].hi, Wa[kt].lo, P, 0, 0, 0);
            P = __builtin_amdgcn_mfma_f32_16x16x32_bf16(A[kt].lo, Wa[kt].hi, P, 0, 0, 0);
            Q = __builtin_amdgcn_mfma_f32_16x16x32_bf16(A[kt].hi, Wb[kt].hi, Q, 0, 0, 0);
            Q = __builtin_amdgcn_mfma_f32_16x16x32_bf16(A[kt].hi, Wb[kt].lo, Q, 0, 0, 0);
            Q = __builtin_amdgcn_mfma_f32_16x16x32_bf16(A[kt].lo, Wb[kt].hi, Q, 0, 0, 0);
        }
        float b1c = b1[w * 16 + lr];
#pragma unroll
        for (int r = 0; r < 4; ++r) {
            size_t off = (size_t)(p0 + lg * 4 + r) * CC + w * 16 + lr;
            base[off] = P[r] - Q[r] + b1c;
            fb[off] = Q[r];
        }
    } else if (bid < 2048) {
        // ---- k1b: xT + x2 (bit-identical to R18 k1b) ----
        int p0 = (bid - 1024) * 16;
#pragma unroll
        for (int q = 0; q < 4; ++q) {
            int pl = w * 4 + q;
            float xv = x[((size_t)(p0 + pl) << 6) + lane];
            sX[pl][lane] = xv;
            float sq = xv * xv;
            for (int off = 32; off; off >>= 1) sq += __shfl_xor(sq, off);   // bit-frozen
            if (lane == 0) x2[p0 + pl] = sq;
        }
        __syncthreads();
        int t = threadIdx.x;
        int b = p0 >> 10, nb = p0 & 1023;
        int d = t >> 2, q4 = (t & 3) << 2;
        float4 v;
        v.x = sX[q4 + 0][d]; v.y = sX[q4 + 1][d]; v.z = sX[q4 + 2][d]; v.w = sX[q4 + 3][d];
        *(float4*)&xT[(((size_t)(b << 6) + d) << 10) + nb + q4] = v;
    } else {
        // ---- k0: counts + keff (256-thread variant, proven in R10/R11) ----
        const unsigned char* mb = (const unsigned char*)maskp;
        const int* mi = (const int*)maskp;
        bool bytelayout = (mb[1] != 0);
        for (int bq = 0; bq < 4; ++bq) {
            int bb = w * 4 + bq;
            int s = 0;
            for (int i = 0; i < 16; ++i) {
                int nn2 = lane + (i << 6);
                int v = bytelayout ? (mb[bb * NN + nn2] ? 1 : 0)
                                   : (mi[bb * NN + nn2] ? 1 : 0);
                s += v;
            }
            for (int off = 32; off; off >>= 1) s += __shfl_xor(s, off);
            if (lane == 0) scnt[bb] = s;
        }
        __syncthreads();
        int t = threadIdx.x;
        if (t < BB) {
            int minc = scnt[0];
            for (int qq = 1; qq < BB; ++qq) minc = min(minc, scnt[qq]);
            int kglob = min(KMAX, max(1, minc - 1));
            float c = (float)scnt[t];
            float v = sqrtf(c / 50.0f) * 8.0f;
            v = fminf(fmaxf(v, 8.0f), 20.0f);
            int kper = (int)v;
            counts[t] = scnt[t];
            keff[t] = min(kper, kglob);
        }
    }
}

// ---------- k2 helpers ----------
#define CE(a, b)                                                      \
    {                                                                 \
        bool sw_ = pk[b] < pk[a];                                     \
        u64 ta_ = pk[a];                                              \
        pk[a] = sw_ ? pk[b] : pk[a];                                  \
        pk[b] = sw_ ? ta_ : pk[b];                                    \
    }

__device__ __forceinline__ u64 head16(const u64 (&pk)[16]) {
    u64 h01 = umin64(pk[0], pk[1]),   h23 = umin64(pk[2], pk[3]);
    u64 h45 = umin64(pk[4], pk[5]),   h67 = umin64(pk[6], pk[7]);
    u64 h89 = umin64(pk[8], pk[9]),   hab = umin64(pk[10], pk[11]);
    u64 hcd = umin64(pk[12], pk[13]), hef = umin64(pk[14], pk[15]);
    return umin64(umin64(umin64(h01, h23), umin64(h45, h67)),
                  umin64(umin64(h89, hab), umin64(hcd, hef)));
}

// exact fallback: Batcher sort + pop (provably identical order to jax top_k)
__device__ __forceinline__ int sortpop(u64 (&pk)[16], int kef, int lane) {
    CE(0,1) CE(2,3) CE(4,5) CE(6,7) CE(8,9) CE(10,11) CE(12,13) CE(14,15)
    CE(0,2) CE(1,3) CE(4,6) CE(5,7) CE(8,10) CE(9,11) CE(12,14) CE(13,15)
    CE(1,2) CE(5,6) CE(9,10) CE(13,14)
    CE(0,4) CE(1,5) CE(2,6) CE(3,7) CE(8,12) CE(9,13) CE(10,14) CE(11,15)
    CE(2,4) CE(3,5) CE(10,12) CE(11,13)
    CE(1,2) CE(3,4) CE(5,6) CE(9,10) CE(11,12) CE(13,14)
    CE(0,8) CE(1,9) CE(2,10) CE(3,11) CE(4,12) CE(5,13) CE(6,14) CE(7,15)
    CE(4,8) CE(5,9) CE(6,10) CE(7,11)
    CE(2,4) CE(3,5) CE(6,8) CE(7,9) CE(10,12) CE(11,13)
    CE(1,2) CE(3,4) CE(5,6) CE(7,8) CE(9,10) CE(11,12) CE(13,14)
    u64 myhead = pk[0];
    int my_m = 0;
    for (int j = 0; j < kef; ++j) {
        u64 g = myhead;
        for (int off = 32; off; off >>= 1) {
            u64 o = __shfl_xor(g, off);
            g = (o < g) ? o : g;
        }
        my_m = (j == lane) ? (int)(unsigned)(g & 0xffffffffu) : my_m;
        bool win = (myhead == g);
#pragma unroll
        for (int tt = 0; tt < 15; ++tt) pk[tt] = win ? pk[tt + 1] : pk[tt];
        pk[15] = win ? ~0ULL : pk[15];
        myhead = pk[0];
    }
    return my_m;
}

// per-row FMA step: acc pairs via v_pk_fma_f32, scalar row value broadcast.
#define ROWFMA(r, rv, cv)                                                        \
    {                                                                            \
        axy[r] = __builtin_elementwise_fma((f32x2){rv, rv}, (f32x2){cv.x, cv.y}, \
                                           axy[r]);                              \
        azw[r] = __builtin_elementwise_fma((f32x2){rv, rv}, (f32x2){cv.z, cv.w}, \
                                           azw[r]);                              \
    }

// ---------------- K2: GEMM-style dist + 16-bit radix threshold/compact/rank top-k ----------------
__global__ __launch_bounds__(256) void k2_knn(const float* __restrict__ x,
                                              const float* __restrict__ xT,
                                              const float* __restrict__ x2,
                                              const int* __restrict__ counts,
                                              const int* __restrict__ keff,
                                              int* __restrict__ idx) {
    __shared__ float sD[ROWS][NN];
    __shared__ float sX2[NN];
    int b = blockIdx.x >> 7;
    int n0 = (blockIdx.x & 127) * ROWS;
    int cnt = counts[b];
    if (n0 >= cnt) return;                  // whole block's rows invalid
    int kef = keff[b];
    int w = threadIdx.x >> 6, lane = threadIdx.x & 63;
    int t = threadIdx.x;
    *(float4*)&sX2[t << 2] = *(const float4*)(x2 + (b << 10) + (t << 2));
    __syncthreads();

    // GEMM phase: wave w covers candidate band [w*256, w*256+256); skip if beyond cnt
    if ((w << 8) < cnt) {
        f32x2 axy[ROWS], azw[ROWS];
#pragma unroll
        for (int r = 0; r < ROWS; ++r) { axy[r] = (f32x2){0.f, 0.f}; azw[r] = (f32x2){0.f, 0.f}; }
        const float* xTb = xT + ((size_t)b << 16);
        const float* xrow0 = x + ((size_t)(b << 10) + n0) * DD;   // blockIdx-uniform
        int c0 = (w << 8) + (lane << 2);
        for (int d0 = 0; d0 < DD; d0 += 4) {
            float4 cv0 = *(const float4*)(xTb + ((size_t)(d0 + 0) << 10) + c0);
            float4 cv1 = *(const float4*)(xTb + ((size_t)(d0 + 1) << 10) + c0);
            float4 cv2 = *(const float4*)(xTb + ((size_t)(d0 + 2) << 10) + c0);
            float4 cv3 = *(const float4*)(xTb + ((size_t)(d0 + 3) << 10) + c0);
#pragma unroll
            for (int r = 0; r < ROWS; ++r) {
                float4 rv = *(const float4*)(xrow0 + r * DD + d0);
                ROWFMA(r, rv.x, cv0)
                ROWFMA(r, rv.y, cv1)
                ROWFMA(r, rv.z, cv2)
                ROWFMA(r, rv.w, cv3)
            }
        }
#pragma unroll
        for (int r = 0; r < ROWS; ++r)
            *(float4*)&sD[r][c0] = make_float4(axy[r].x, axy[r].y, azw[r].x, azw[r].y);
    }
    __syncthreads();

    // selection: rows rA=w, rB=w+4 interleaved
    int rA = w, rB = w + 4;
    int nA = n0 + rA, nB = n0 + rB;
    bool vA = nA < cnt, vB = nB < cnt;      // wave-uniform; vB implies vA
    if (!vA) return;
    float x2A = sX2[nA];
    float x2B = sX2[nB & 1023];
    u64 pkA[16], pkB[16];
#pragma unroll
    for (int tt = 0; tt < 16; ++tt) {
        int c = (tt << 6) + lane;
        float dA = fmaxf((x2A + sX2[c]) - 2.0f * sD[rA][c], 0.0f);
        float dB = fmaxf((x2B + sX2[c]) - 2.0f * sD[rB][c], 0.0f);
        pkA[tt] = (c < cnt && c != nA)
            ? (((u64)__float_as_uint(dA) << 32) | (unsigned)c) : ~0ULL;
        pkB[tt] = (vB && c < cnt && c != nB)
            ? (((u64)__float_as_uint(dB) << 32) | (unsigned)c) : ~0ULL;
    }
    u64 hA = head16(pkA), hB = head16(pkB);
    // kef-th smallest head's TOP-16 dist bits via radix-select (16 serial steps)
    unsigned hTA = (unsigned)(hA >> 48), hTB = (unsigned)(hB >> 48);
    unsigned prefA = 0u, prefB = 0u;
    int rankA = kef, rankB = kef;
#pragma unroll
    for (int bbit = 15; bbit >= 0; --bbit) {
        unsigned bitm = 1u << bbit;
        bool cA = (((hTA ^ prefA) >> (bbit + 1)) == 0) && ((hTA & bitm) == 0);
        bool cB = (((hTB ^ prefB) >> (bbit + 1)) == 0) && ((hTB & bitm) == 0);
        u64 mA = __ballot(cA);
        u64 mB = __ballot(cB);
        int nA0 = __popcll(mA), nB0 = __popcll(mB);
        if (rankA > nA0) { rankA -= nA0; prefA |= bitm; }
        if (rankB > nB0) { rankB -= nB0; prefB |= bitm; }
    }
    // threshold: keep all with top-16 dist bits <= kth head's (superset bound)
    u64 t0A = ((u64)((prefA << 16) | 0xFFFFu) << 32) | 0xFFFFFFFFULL;
    u64 t0B = vB ? (((u64)((prefB << 16) | 0xFFFFu) << 32) | 0xFFFFFFFFULL) : 0ULL;

    // ballot-compaction into LDS (unordered; rank pass restores exact order)
    u64* svA = (u64*)&sD[rA][0];            // rows rA/rB now wave-exclusive
    u64* svB = (u64*)&sD[rB][0];
    u64 lmask = (lane == 0) ? 0ULL : ((~0ULL) >> (64 - lane));
    int SA = 0, SB = 0;
#pragma unroll
    for (int i = 0; i < 16; ++i) {
        bool qA = (pkA[i] <= t0A);
        bool qB = (pkB[i] <= t0B);
        u64 mA = __ballot(qA);
        u64 mB = __ballot(qB);
        if (qA) svA[SA + __popcll(mA & lmask)] = pkA[i];
        if (qB) svB[SB + __popcll(mB & lmask)] = pkB[i];
        SA += __popcll(mA);
        SB += __popcll(mB);
    }
    size_t prowA = (size_t)(b << 10) + nA;
    size_t prowB = (size_t)(b << 10) + nB;
    if (SA <= 64 && SB <= 64) {
        u64 sA = (lane < SA) ? svA[lane] : ~0ULL;
        u64 sB = (lane < SB) ? svB[lane] : ~0ULL;
        int rkA = 0, rkB = 0;
        int SM = max(SA, SB);
        for (int j = 0; j < SM; ++j) {       // wave-uniform bound
            u64 aj = svA[j];
            u64 bj = svB[j];
            rkA += (j < SA && aj < sA) ? 1 : 0;
            rkB += (j < SB && bj < sB) ? 1 : 0;
        }
        if (rkA < kef && lane < SA) idx[prowA * KMAX + rkA] = (int)(unsigned)(sA & 0xffffffffu);
        if (lane >= kef && lane < KMAX) idx[prowA * KMAX + lane] = 0;
        if (vB) {
            if (rkB < kef && lane < SB) idx[prowB * KMAX + rkB] = (int)(unsigned)(sB & 0xffffffffu);
            if (lane >= kef && lane < KMAX) idx[prowB * KMAX + lane] = 0;
        }
    } else {
        int mA = sortpop(pkA, kef, lane);
        if (lane < KMAX) idx[prowA * KMAX + lane] = (lane < kef) ? mA : 0;
        if (vB) {
            int mB = sortpop(pkB, kef, lane);
            if (lane < KMAX) idx[prowB * KMAX + lane] = (lane < kef) ? mB : 0;
        }
    }
}

// ---------------- K3: gather + GN + ReLU + (H@W2 via MFMA) + maxpool ----------------
__global__ __launch_bounds__(256, 2) void k3_mlp(const float* __restrict__ base,
                                                 const float* __restrict__ fb,
                                                 const int* __restrict__ idx,
                                                 const int* __restrict__ counts,
                                                 const float* __restrict__ gamma,
                                                 const float* __restrict__ beta,
                                                 const float* __restrict__ W2,
                                                 const float* __restrict__ b2,
                                                 float* __restrict__ out) {
    __shared__ float sC[4][64][20];         // [20] pad: 16B-aligned float4 rows
    int w = threadIdx.x >> 6, lane = threadIdx.x & 63;
    int lg = lane >> 4, lr = lane & 15;
    int p0 = blockIdx.x * 16;
    int b = p0 >> 10;
    int n0b = p0 & 1023;
    int cnt = counts[b];
    int pt = p0 + lr;                       // point this lane feeds into A-frag
    bool aval = (n0b + lr) < cnt;

    // B-frags: W2[kt*32+lg*8+e][nt*16+lr], bf16-packed, wave-uniform weights
    bf16x8 Bf[4][2];
#pragma unroll
    for (int nt = 0; nt < 4; ++nt)
#pragma unroll
        for (int kt = 0; kt < 2; ++kt) {
            float4 lo, hi;
            const float* wp = W2 + (size_t)(kt * 32 + lg * 8) * CC + nt * 16 + lr;
            lo.x = wp[0 * CC]; lo.y = wp[1 * CC]; lo.z = wp[2 * CC]; lo.w = wp[3 * CC];
            hi.x = wp[4 * CC]; hi.y = wp[5 * CC]; hi.z = wp[6 * CC]; hi.w = wp[7 * CC];
            Bf[nt][kt] = pack8(lo, hi);
        }

    // per-lane channel blocks: cA = lg*8..+7, cB = 32+lg*8..+7
    const float* bp = base + (size_t)pt * CC + lg * 8;
    float4 baA0 = *(const float4*)(bp);
    float4 baA1 = *(const float4*)(bp + 4);
    float4 baB0 = *(const float4*)(bp + 32);
    float4 baB1 = *(const float4*)(bp + 36);
    const float* gp = gamma + lg * 8;
    float4 gA0 = *(const float4*)(gp),      gA1 = *(const float4*)(gp + 4);
    float4 gB0 = *(const float4*)(gp + 32), gB1 = *(const float4*)(gp + 36);
    const float* bep = beta + lg * 8;
    float4 eA0 = *(const float4*)(bep),      eA1 = *(const float4*)(bep + 4);
    float4 eB0 = *(const float4*)(bep + 32), eB1 = *(const float4*)(bep + 36);

    const float* fbb = fb + ((size_t)(b << 10)) * CC;
    const int* idxp = idx + (size_t)pt * KMAX;

    f32x4v cmax[4];
#pragma unroll
    for (int nt = 0; nt < 4; ++nt) cmax[nt] = (f32x4v){-1e30f, -1e30f, -1e30f, -1e30f};

#pragma unroll
    for (int jj = 0; jj < 5; ++jj) {
        int j = w * 5 + jj;
        int m = aval ? idxp[j] : 0;         // guard poisoned idx of invalid rows
        const float* fr = fbb + (size_t)m * CC + lg * 8;
        float4 hA0 = *(const float4*)(fr);
        float4 hA1 = *(const float4*)(fr + 4);
        float4 hB0 = *(const float4*)(fr + 32);
        float4 hB1 = *(const float4*)(fr + 36);
        hA0.x += baA0.x; hA0.y += baA0.y; hA0.z += baA0.z; hA0.w += baA0.w;
        hA1.x += baA1.x; hA1.y += baA1.y; hA1.z += baA1.z; hA1.w += baA1.w;
        hB0.x += baB0.x; hB0.y += baB0.y; hB0.z += baB0.z; hB0.w += baB0.w;
        hB1.x += baB1.x; hB1.y += baB1.y; hB1.z += baB1.z; hB1.w += baB1.w;
        gn4(hA0, gA0, eA0);
        gn4(hA1, gA1, eA1);
        gn4(hB0, gB0, eB0);
        gn4(hB1, gB1, eB1);
        bf16x8 A0 = pack8(hA0, hA1);        // k = 0..31 slice for this lane
        bf16x8 A1 = pack8(hB0, hB1);        // k = 32..63 slice
#pragma unroll
        for (int nt = 0; nt < 4; ++nt) {
            f32x4v c = {0.f, 0.f, 0.f, 0.f};
            c = __builtin_amdgcn_mfma_f32_16x16x32_bf16(A0, Bf[nt][0], c, 0, 0, 0);
            c = __builtin_amdgcn_mfma_f32_16x16x32_bf16(A1, Bf[nt][1], c, 0, 0, 0);
            cmax[nt].x = fmaxf(cmax[nt].x, c.x);
            cmax[nt].y = fmaxf(cmax[nt].y, c.y);
            cmax[nt].z = fmaxf(cmax[nt].z, c.z);
            cmax[nt].w = fmaxf(cmax[nt].w, c.w);
        }
    }
#pragma unroll
    for (int nt = 0; nt < 4; ++nt)
        *(float4*)&sC[w][lane][nt * 4] = (float4){cmax[nt].x, cmax[nt].y, cmax[nt].z, cmax[nt].w};
    __syncthreads();
    // wave w writes rows R = w*4+q, lane = output column (coalesced 256B stores)
    float b2c = b2[lane];
#pragma unroll
    for (int q = 0; q < 4; ++q) {
        int R = w * 4 + q;                              // local row 0..15
        int src = ((R >> 2) << 4) + lr;                 // source lane
        int reg = (lg << 2) + (R & 3);                  // source reg slot
        float v = fmaxf(fmaxf(sC[0][src][reg], sC[1][src][reg]),
                        fmaxf(sC[2][src][reg], sC[3][src][reg]));
        bool valid = (n0b + R) < cnt;
        out[(size_t)(p0 + R) * CC + lane] = valid ? (v + b2c) : 0.f;
    }
}

extern "C" void kernel_launch(void* const* d_in, const int* in_sizes, int n_in,
                              void* d_out, int out_size, void* d_ws, size_t ws_size,
                              hipStream_t stream) {
    const float* x     = (const float*)d_in[0];
    const void*  maskp = d_in[1];
    const float* W1    = (const float*)d_in[2];
    const float* b1    = (const float*)d_in[3];
    const float* gamma = (const float*)d_in[4];
    const float* beta  = (const float*)d_in[5];
    const float* W2    = (const float*)d_in[6];
    const float* b2    = (const float*)d_in[7];
    float* out = (float*)d_out;

    int* d_counts = (int*)d_ws;
    int* d_keff   = d_counts + 16;
    float* d_x2   = (float*)(d_counts + 32);
    float* d_base = d_x2 + BB * NN;
    float* d_fb   = d_base + (size_t)BB * NN * CC;
    int* d_idx    = (int*)(d_fb + (size_t)BB * NN * CC);
    float* d_xT   = (float*)d_out;   // free until k3

    hipLaunchKernelGGL(k1_fused, dim3(2049), dim3(256), 0, stream,
                       x, W1, b1, d_base, d_fb, d_xT, d_x2, maskp, d_counts, d_keff);
    hipLaunchKernelGGL(k2_knn, dim3(BB * (NN / ROWS)), dim3(256), 0, stream,
                       x, d_xT, d_x2, d_counts, d_keff, d_idx);
    hipLaunchKernelGGL(k3_mlp, dim3(BB * NN / 16), dim3(256), 0, stream,
                       d_base, d_fb, d_idx, d_counts, gamma, beta, W2, b2, out);
}

// Round 20
// 82.668 us; speedup vs baseline: 1.0681x; 1.0681x over previous
//
#include <hip/hip_runtime.h>
#include <stdint.h>

#define BB 16
#define NN 1024
#define DD 64
#define CC 64
#define KMAX 20
#define ROWS 8

typedef unsigned long long u64;
typedef float f32x2 __attribute__((ext_vector_type(2)));
typedef float f32x4v __attribute__((ext_vector_type(4)));
typedef short bf16x8 __attribute__((ext_vector_type(8)));

__device__ inline u64 umin64(u64 a, u64 b) { return a < b ? a : b; }

__device__ inline unsigned f2bf(float f) {        // fp32 -> bf16 bits, RNE
    unsigned u = __float_as_uint(f);
    return (u + 0x7FFFu + ((u >> 16) & 1u)) >> 16;
}

__device__ inline bf16x8 pack8(const float4 a, const float4 b) {
    union { unsigned u[4]; bf16x8 v; } r;
    r.u[0] = f2bf(a.x) | (f2bf(a.y) << 16);
    r.u[1] = f2bf(a.z) | (f2bf(a.w) << 16);
    r.u[2] = f2bf(b.x) | (f2bf(b.y) << 16);
    r.u[3] = f2bf(b.z) | (f2bf(b.w) << 16);
    return r.v;
}

struct bfpair { bf16x8 hi, lo; };
__device__ __forceinline__ bfpair split8(const float v[8]) {
    union { unsigned u[4]; bf16x8 x; } H, L;
#pragma unroll
    for (int i = 0; i < 4; ++i) {
        unsigned h0 = f2bf(v[2 * i]), h1 = f2bf(v[2 * i + 1]);
        float r0 = v[2 * i] - __uint_as_float(h0 << 16);
        float r1 = v[2 * i + 1] - __uint_as_float(h1 << 16);
        H.u[i] = h0 | (h1 << 16);
        L.u[i] = f2bf(r0) | (f2bf(r1) << 16);
    }
    bfpair r; r.hi = H.x; r.lo = L.x; return r;
}

// GroupNorm on one group of 4 channels (lane-local), + gamma/beta + ReLU
__device__ inline void gn4(float4& h, const float4 g, const float4 be) {
    float mu = (h.x + h.y + h.z + h.w) * 0.25f;
    float dx = h.x - mu, dy = h.y - mu, dz = h.z - mu, dw = h.w - mu;
    float var = (dx * dx + dy * dy + dz * dz + dw * dw) * 0.25f;
    float rs = __builtin_amdgcn_rsqf(var + 1e-5f);
    h.x = fmaxf(fmaf(dx * rs, g.x, be.x), 0.f);
    h.y = fmaxf(fmaf(dy * rs, g.y, be.y), 0.f);
    h.z = fmaxf(fmaf(dz * rs, g.z, be.z), 0.f);
    h.w = fmaxf(fmaf(dw * rs, g.w, be.w), 0.f);
}

// ---------------- K0: counts + k_eff (one block) ----------------
__global__ void k0_counts(const void* __restrict__ maskp,
                          int* __restrict__ counts, int* __restrict__ keff) {
    __shared__ int scnt[BB];
    int tid = threadIdx.x;
    int w = tid >> 6, lane = tid & 63;
    const unsigned char* mb = (const unsigned char*)maskp;
    const int* mi = (const int*)maskp;
    bool bytelayout = (mb[1] != 0);
    int s = 0;
    for (int i = 0; i < 16; ++i) {
        int n = lane + (i << 6);
        int v = bytelayout ? (mb[w * NN + n] ? 1 : 0) : (mi[w * NN + n] ? 1 : 0);
        s += v;
    }
    for (int off = 32; off; off >>= 1) s += __shfl_xor(s, off);
    if (lane == 0) scnt[w] = s;
    __syncthreads();
    if (tid < BB) {
        int minc = scnt[0];
        for (int q = 1; q < BB; ++q) minc = min(minc, scnt[q]);
        int kglob = min(KMAX, max(1, minc - 1));
        float c = (float)scnt[tid];
        float v = sqrtf(c / 50.0f) * 8.0f;
        v = fminf(fmaxf(v, 8.0f), 20.0f);
        int kper = (int)v;
        counts[tid] = scnt[tid];
        keff[tid] = min(kper, kglob);
    }
}

// ---------------- K1a: feats only (split-bf16 MFMA), f32 output ----------------
// block = 16 points, 4 waves; wave w computes out-channel stripe nt=w (16 cols).
// P = x@W1a, Q = x@W1b as hi@hi + hi@lo + lo@hi (err ~2^-18, f32-grade).
__global__ __launch_bounds__(256) void k1a_feats(const float* __restrict__ x,
                                                 const float* __restrict__ W1,
                                                 const float* __restrict__ b1,
                                                 float* __restrict__ base,
                                                 float* __restrict__ fb) {
    int w = threadIdx.x >> 6, lane = threadIdx.x & 63;
    int lg = lane >> 4, lr = lane & 15;
    int p0 = blockIdx.x * 16;

    // A-frags: lane l holds point row (l&15), k=(l>>4)*8+e
    float av[8];
    bfpair A[2];
    {
        const float* xr = x + (size_t)(p0 + lr) * DD;
#pragma unroll
        for (int kt = 0; kt < 2; ++kt) {
            float4 a0 = *(const float4*)(xr + kt * 32 + lg * 8);
            float4 a1 = *(const float4*)(xr + kt * 32 + lg * 8 + 4);
            av[0] = a0.x; av[1] = a0.y; av[2] = a0.z; av[3] = a0.w;
            av[4] = a1.x; av[5] = a1.y; av[6] = a1.z; av[7] = a1.w;
            A[kt] = split8(av);
        }
    }
    // B-frags for stripe nt=w: col w*16+lr, k=(l>>4)*8+e
    bfpair Wa[2], Wb[2];
#pragma unroll
    for (int kt = 0; kt < 2; ++kt) {
        const float* wpa = W1 + (size_t)(kt * 32 + lg * 8) * CC + w * 16 + lr;
        float wv[8];
#pragma unroll
        for (int e = 0; e < 8; ++e) wv[e] = wpa[e * CC];
        Wa[kt] = split8(wv);
        const float* wpb = wpa + (size_t)DD * CC;
#pragma unroll
        for (int e = 0; e < 8; ++e) wv[e] = wpb[e * CC];
        Wb[kt] = split8(wv);
    }

    f32x4v P = {0, 0, 0, 0}, Q = {0, 0, 0, 0};
#pragma unroll
    for (int kt = 0; kt < 2; ++kt) {
        P = __builtin_amdgcn_mfma_f32_16x16x32_bf16(A[kt].hi, Wa[kt].hi, P, 0, 0, 0);
        P = __builtin_amdgcn_mfma_f32_16x16x32_bf16(A[kt].hi, Wa[kt].lo, P, 0, 0, 0);
        P = __builtin_amdgcn_mfma_f32_16x16x32_bf16(A[kt].lo, Wa[kt].hi, P, 0, 0, 0);
        Q = __builtin_amdgcn_mfma_f32_16x16x32_bf16(A[kt].hi, Wb[kt].hi, Q, 0, 0, 0);
        Q = __builtin_amdgcn_mfma_f32_16x16x32_bf16(A[kt].hi, Wb[kt].lo, Q, 0, 0, 0);
        Q = __builtin_amdgcn_mfma_f32_16x16x32_bf16(A[kt].lo, Wb[kt].hi, Q, 0, 0, 0);
    }
    // C/D: lane l reg r -> local row (l>>4)*4+r, col w*16+(l&15)
    {
        float b1c = b1[w * 16 + lr];
#pragma unroll
        for (int r = 0; r < 4; ++r) {
            size_t off = (size_t)(p0 + lg * 4 + r) * CC + w * 16 + lr;
            base[off] = P[r] - Q[r] + b1c;
            fb[off] = Q[r];
        }
    }
}

// ---------------- K1b: xT + x2 only (streaming transpose) ----------------
__global__ __launch_bounds__(256) void k1b_xt(const float* __restrict__ x,
                                              float* __restrict__ xT,
                                              float* __restrict__ x2) {
    __shared__ float sX[16][65];
    int w = threadIdx.x >> 6, lane = threadIdx.x & 63;
    int p0 = blockIdx.x * 16;
#pragma unroll
    for (int q = 0; q < 4; ++q) {
        int pl = w * 4 + q;
        float xv = x[((size_t)(p0 + pl) << 6) + lane];
        sX[pl][lane] = xv;
        float sq = xv * xv;
        for (int off = 32; off; off >>= 1) sq += __shfl_xor(sq, off);   // bit-frozen tree
        if (lane == 0) x2[p0 + pl] = sq;
    }
    __syncthreads();
    int t = threadIdx.x;
    int b = p0 >> 10, nb = p0 & 1023;
    int d = t >> 2, q4 = (t & 3) << 2;        // 4 threads per d-row, 4 floats each
    float4 v;
    v.x = sX[q4 + 0][d]; v.y = sX[q4 + 1][d]; v.z = sX[q4 + 2][d]; v.w = sX[q4 + 3][d];
    *(float4*)&xT[(((size_t)(b << 6) + d) << 10) + nb + q4] = v;
}

// ---------- k2 helpers ----------
#define CE(a, b)                                                      \
    {                                                                 \
        bool sw_ = pk[b] < pk[a];                                     \
        u64 ta_ = pk[a];                                              \
        pk[a] = sw_ ? pk[b] : pk[a];                                  \
        pk[b] = sw_ ? ta_ : pk[b];                                    \
    }

__device__ __forceinline__ u64 head16(const u64 (&pk)[16]) {
    u64 h01 = umin64(pk[0], pk[1]),   h23 = umin64(pk[2], pk[3]);
    u64 h45 = umin64(pk[4], pk[5]),   h67 = umin64(pk[6], pk[7]);
    u64 h89 = umin64(pk[8], pk[9]),   hab = umin64(pk[10], pk[11]);
    u64 hcd = umin64(pk[12], pk[13]), hef = umin64(pk[14], pk[15]);
    return umin64(umin64(umin64(h01, h23), umin64(h45, h67)),
                  umin64(umin64(h89, hab), umin64(hcd, hef)));
}

// exact fallback: Batcher sort + pop (provably identical order to jax top_k)
__device__ __forceinline__ int sortpop(u64 (&pk)[16], int kef, int lane) {
    CE(0,1) CE(2,3) CE(4,5) CE(6,7) CE(8,9) CE(10,11) CE(12,13) CE(14,15)
    CE(0,2) CE(1,3) CE(4,6) CE(5,7) CE(8,10) CE(9,11) CE(12,14) CE(13,15)
    CE(1,2) CE(5,6) CE(9,10) CE(13,14)
    CE(0,4) CE(1,5) CE(2,6) CE(3,7) CE(8,12) CE(9,13) CE(10,14) CE(11,15)
    CE(2,4) CE(3,5) CE(10,12) CE(11,13)
    CE(1,2) CE(3,4) CE(5,6) CE(9,10) CE(11,12) CE(13,14)
    CE(0,8) CE(1,9) CE(2,10) CE(3,11) CE(4,12) CE(5,13) CE(6,14) CE(7,15)
    CE(4,8) CE(5,9) CE(6,10) CE(7,11)
    CE(2,4) CE(3,5) CE(6,8) CE(7,9) CE(10,12) CE(11,13)
    CE(1,2) CE(3,4) CE(5,6) CE(7,8) CE(9,10) CE(11,12) CE(13,14)
    u64 myhead = pk[0];
    int my_m = 0;
    for (int j = 0; j < kef; ++j) {
        u64 g = myhead;
        for (int off = 32; off; off >>= 1) {
            u64 o = __shfl_xor(g, off);
            g = (o < g) ? o : g;
        }
        my_m = (j == lane) ? (int)(unsigned)(g & 0xffffffffu) : my_m;
        bool win = (myhead == g);
#pragma unroll
        for (int tt = 0; tt < 15; ++tt) pk[tt] = win ? pk[tt + 1] : pk[tt];
        pk[15] = win ? ~0ULL : pk[15];
        myhead = pk[0];
    }
    return my_m;
}

// per-row FMA step: acc pairs via v_pk_fma_f32, scalar row value broadcast.
#define ROWFMA(r, rv, cv)                                                        \
    {                                                                            \
        axy[r] = __builtin_elementwise_fma((f32x2){rv, rv}, (f32x2){cv.x, cv.y}, \
                                           axy[r]);                              \
        azw[r] = __builtin_elementwise_fma((f32x2){rv, rv}, (f32x2){cv.z, cv.w}, \
                                           azw[r]);                              \
    }

// ---------------- K2: GEMM-style dist + 16-bit radix threshold/compact/rank top-k ----------------
__global__ __launch_bounds__(256) void k2_knn(const float* __restrict__ x,
                                              const float* __restrict__ xT,
                                              const float* __restrict__ x2,
                                              const int* __restrict__ counts,
                                              const int* __restrict__ keff,
                                              int* __restrict__ idx) {
    __shared__ float sD[ROWS][NN];
    __shared__ float sX2[NN];
    int b = blockIdx.x >> 7;
    int n0 = (blockIdx.x & 127) * ROWS;
    int cnt = counts[b];
    if (n0 >= cnt) return;                  // whole block's rows invalid
    int kef = keff[b];
    int w = threadIdx.x >> 6, lane = threadIdx.x & 63;
    int t = threadIdx.x;
    *(float4*)&sX2[t << 2] = *(const float4*)(x2 + (b << 10) + (t << 2));
    __syncthreads();

    // GEMM phase: wave w covers candidate band [w*256, w*256+256); skip if beyond cnt
    if ((w << 8) < cnt) {
        f32x2 axy[ROWS], azw[ROWS];
#pragma unroll
        for (int r = 0; r < ROWS; ++r) { axy[r] = (f32x2){0.f, 0.f}; azw[r] = (f32x2){0.f, 0.f}; }
        const float* xTb = xT + ((size_t)b << 16);
        const float* xrow0 = x + ((size_t)(b << 10) + n0) * DD;   // blockIdx-uniform
        int c0 = (w << 8) + (lane << 2);
        for (int d0 = 0; d0 < DD; d0 += 4) {
            float4 cv0 = *(const float4*)(xTb + ((size_t)(d0 + 0) << 10) + c0);
            float4 cv1 = *(const float4*)(xTb + ((size_t)(d0 + 1) << 10) + c0);
            float4 cv2 = *(const float4*)(xTb + ((size_t)(d0 + 2) << 10) + c0);
            float4 cv3 = *(const float4*)(xTb + ((size_t)(d0 + 3) << 10) + c0);
#pragma unroll
            for (int r = 0; r < ROWS; ++r) {
                float4 rv = *(const float4*)(xrow0 + r * DD + d0);
                ROWFMA(r, rv.x, cv0)
                ROWFMA(r, rv.y, cv1)
                ROWFMA(r, rv.z, cv2)
                ROWFMA(r, rv.w, cv3)
            }
        }
#pragma unroll
        for (int r = 0; r < ROWS; ++r)
            *(float4*)&sD[r][c0] = make_float4(axy[r].x, axy[r].y, azw[r].x, azw[r].y);
    }
    __syncthreads();

    // selection: rows rA=w, rB=w+4 interleaved
    int rA = w, rB = w + 4;
    int nA = n0 + rA, nB = n0 + rB;
    bool vA = nA < cnt, vB = nB < cnt;      // wave-uniform; vB implies vA
    if (!vA) return;
    float x2A = sX2[nA];
    float x2B = sX2[nB & 1023];
    u64 pkA[16], pkB[16];
#pragma unroll
    for (int tt = 0; tt < 16; ++tt) {
        int c = (tt << 6) + lane;
        float dA = fmaxf((x2A + sX2[c]) - 2.0f * sD[rA][c], 0.0f);
        float dB = fmaxf((x2B + sX2[c]) - 2.0f * sD[rB][c], 0.0f);
        pkA[tt] = (c < cnt && c != nA)
            ? (((u64)__float_as_uint(dA) << 32) | (unsigned)c) : ~0ULL;
        pkB[tt] = (vB && c < cnt && c != nB)
            ? (((u64)__float_as_uint(dB) << 32) | (unsigned)c) : ~0ULL;
    }
    u64 hA = head16(pkA), hB = head16(pkB);
    // kef-th smallest head's TOP-16 dist bits via radix-select (16 serial steps)
    unsigned hTA = (unsigned)(hA >> 48), hTB = (unsigned)(hB >> 48);
    unsigned prefA = 0u, prefB = 0u;
    int rankA = kef, rankB = kef;
#pragma unroll
    for (int bbit = 15; bbit >= 0; --bbit) {
        unsigned bitm = 1u << bbit;
        bool cA = (((hTA ^ prefA) >> (bbit + 1)) == 0) && ((hTA & bitm) == 0);
        bool cB = (((hTB ^ prefB) >> (bbit + 1)) == 0) && ((hTB & bitm) == 0);
        u64 mA = __ballot(cA);
        u64 mB = __ballot(cB);
        int nA0 = __popcll(mA), nB0 = __popcll(mB);
        if (rankA > nA0) { rankA -= nA0; prefA |= bitm; }
        if (rankB > nB0) { rankB -= nB0; prefB |= bitm; }
    }
    // threshold: keep all with top-16 dist bits <= kth head's (superset bound)
    u64 t0A = ((u64)((prefA << 16) | 0xFFFFu) << 32) | 0xFFFFFFFFULL;
    u64 t0B = vB ? (((u64)((prefB << 16) | 0xFFFFu) << 32) | 0xFFFFFFFFULL) : 0ULL;

    // ballot-compaction into LDS (unordered; rank pass restores exact order)
    u64* svA = (u64*)&sD[rA][0];            // rows rA/rB now wave-exclusive
    u64* svB = (u64*)&sD[rB][0];
    u64 lmask = (lane == 0) ? 0ULL : ((~0ULL) >> (64 - lane));
    int SA = 0, SB = 0;
#pragma unroll
    for (int i = 0; i < 16; ++i) {
        bool qA = (pkA[i] <= t0A);
        bool qB = (pkB[i] <= t0B);
        u64 mA = __ballot(qA);
        u64 mB = __ballot(qB);
        if (qA) svA[SA + __popcll(mA & lmask)] = pkA[i];
        if (qB) svB[SB + __popcll(mB & lmask)] = pkB[i];
        SA += __popcll(mA);
        SB += __popcll(mB);
    }
    size_t prowA = (size_t)(b << 10) + nA;
    size_t prowB = (size_t)(b << 10) + nB;
    if (SA <= 64 && SB <= 64) {
        u64 sA = (lane < SA) ? svA[lane] : ~0ULL;
        u64 sB = (lane < SB) ? svB[lane] : ~0ULL;
        int rkA = 0, rkB = 0;
        int SM = max(SA, SB);
        for (int j = 0; j < SM; ++j) {       // wave-uniform bound
            u64 aj = svA[j];
            u64 bj = svB[j];
            rkA += (j < SA && aj < sA) ? 1 : 0;
            rkB += (j < SB && bj < sB) ? 1 : 0;
        }
        if (rkA < kef && lane < SA) idx[prowA * KMAX + rkA] = (int)(unsigned)(sA & 0xffffffffu);
        if (lane >= kef && lane < KMAX) idx[prowA * KMAX + lane] = 0;
        if (vB) {
            if (rkB < kef && lane < SB) idx[prowB * KMAX + rkB] = (int)(unsigned)(sB & 0xffffffffu);
            if (lane >= kef && lane < KMAX) idx[prowB * KMAX + lane] = 0;
        }
    } else {
        int mA = sortpop(pkA, kef, lane);
        if (lane < KMAX) idx[prowA * KMAX + lane] = (lane < kef) ? mA : 0;
        if (vB) {
            int mB = sortpop(pkB, kef, lane);
            if (lane < KMAX) idx[prowB * KMAX + lane] = (lane < kef) ? mB : 0;
        }
    }
}

// ---------------- K3: gather + GN + ReLU + (H@W2 via MFMA) + maxpool ----------------
__global__ __launch_bounds__(256, 2) void k3_mlp(const float* __restrict__ base,
                                                 const float* __restrict__ fb,
                                                 const int* __restrict__ idx,
                                                 const int* __restrict__ counts,
                                                 const float* __restrict__ gamma,
                                                 const float* __restrict__ beta,
                                                 const float* __restrict__ W2,
                                                 const float* __restrict__ b2,
                                                 float* __restrict__ out) {
    __shared__ float sC[4][64][20];         // [20] pad: 16B-aligned float4 rows
    int w = threadIdx.x >> 6, lane = threadIdx.x & 63;
    int lg = lane >> 4, lr = lane & 15;
    int p0 = blockIdx.x * 16;
    int b = p0 >> 10;
    int n0b = p0 & 1023;
    int cnt = counts[b];
    int pt = p0 + lr;                       // point this lane feeds into A-frag
    bool aval = (n0b + lr) < cnt;

    // B-frags: W2[kt*32+lg*8+e][nt*16+lr], bf16-packed, wave-uniform weights
    bf16x8 Bf[4][2];
#pragma unroll
    for (int nt = 0; nt < 4; ++nt)
#pragma unroll
        for (int kt = 0; kt < 2; ++kt) {
            float4 lo, hi;
            const float* wp = W2 + (size_t)(kt * 32 + lg * 8) * CC + nt * 16 + lr;
            lo.x = wp[0 * CC]; lo.y = wp[1 * CC]; lo.z = wp[2 * CC]; lo.w = wp[3 * CC];
            hi.x = wp[4 * CC]; hi.y = wp[5 * CC]; hi.z = wp[6 * CC]; hi.w = wp[7 * CC];
            Bf[nt][kt] = pack8(lo, hi);
        }

    // per-lane channel blocks: cA = lg*8..+7, cB = 32+lg*8..+7
    const float* bp = base + (size_t)pt * CC + lg * 8;
    float4 baA0 = *(const float4*)(bp);
    float4 baA1 = *(const float4*)(bp + 4);
    float4 baB0 = *(const float4*)(bp + 32);
    float4 baB1 = *(const float4*)(bp + 36);
    const float* gp = gamma + lg * 8;
    float4 gA0 = *(const float4*)(gp),      gA1 = *(const float4*)(gp + 4);
    float4 gB0 = *(const float4*)(gp + 32), gB1 = *(const float4*)(gp + 36);
    const float* bep = beta + lg * 8;
    float4 eA0 = *(const float4*)(bep),      eA1 = *(const float4*)(bep + 4);
    float4 eB0 = *(const float4*)(bep + 32), eB1 = *(const float4*)(bep + 36);

    const float* fbb = fb + ((size_t)(b << 10)) * CC;
    const int* idxp = idx + (size_t)pt * KMAX;

    f32x4v cmax[4];
#pragma unroll
    for (int nt = 0; nt < 4; ++nt) cmax[nt] = (f32x4v){-1e30f, -1e30f, -1e30f, -1e30f};

#pragma unroll
    for (int jj = 0; jj < 5; ++jj) {
        int j = w * 5 + jj;
        int m = aval ? idxp[j] : 0;         // guard poisoned idx of invalid rows
        const float* fr = fbb + (size_t)m * CC + lg * 8;
        float4 hA0 = *(const float4*)(fr);
        float4 hA1 = *(const float4*)(fr + 4);
        float4 hB0 = *(const float4*)(fr + 32);
        float4 hB1 = *(const float4*)(fr + 36);
        hA0.x += baA0.x; hA0.y += baA0.y; hA0.z += baA0.z; hA0.w += baA0.w;
        hA1.x += baA1.x; hA1.y += baA1.y; hA1.z += baA1.z; hA1.w += baA1.w;
        hB0.x += baB0.x; hB0.y += baB0.y; hB0.z += baB0.z; hB0.w += baB0.w;
        hB1.x += baB1.x; hB1.y += baB1.y; hB1.z += baB1.z; hB1.w += baB1.w;
        gn4(hA0, gA0, eA0);
        gn4(hA1, gA1, eA1);
        gn4(hB0, gB0, eB0);
        gn4(hB1, gB1, eB1);
        bf16x8 A0 = pack8(hA0, hA1);        // k = 0..31 slice for this lane
        bf16x8 A1 = pack8(hB0, hB1);        // k = 32..63 slice
#pragma unroll
        for (int nt = 0; nt < 4; ++nt) {
            f32x4v c = {0.f, 0.f, 0.f, 0.f};
            c = __builtin_amdgcn_mfma_f32_16x16x32_bf16(A0, Bf[nt][0], c, 0, 0, 0);
            c = __builtin_amdgcn_mfma_f32_16x16x32_bf16(A1, Bf[nt][1], c, 0, 0, 0);
            cmax[nt].x = fmaxf(cmax[nt].x, c.x);
            cmax[nt].y = fmaxf(cmax[nt].y, c.y);
            cmax[nt].z = fmaxf(cmax[nt].z, c.z);
            cmax[nt].w = fmaxf(cmax[nt].w, c.w);
        }
    }
#pragma unroll
    for (int nt = 0; nt < 4; ++nt)
        *(float4*)&sC[w][lane][nt * 4] = (float4){cmax[nt].x, cmax[nt].y, cmax[nt].z, cmax[nt].w};
    __syncthreads();
    // wave w writes rows R = w*4+q, lane = output column (coalesced 256B stores)
    float b2c = b2[lane];
#pragma unroll
    for (int q = 0; q < 4; ++q) {
        int R = w * 4 + q;                              // local row 0..15
        int src = ((R >> 2) << 4) + lr;                 // source lane
        int reg = (lg << 2) + (R & 3);                  // source reg slot
        float v = fmaxf(fmaxf(sC[0][src][reg], sC[1][src][reg]),
                        fmaxf(sC[2][src][reg], sC[3][src][reg]));
        bool valid = (n0b + R) < cnt;
        out[(size_t)(p0 + R) * CC + lane] = valid ? (v + b2c) : 0.f;
    }
}

extern "C" void kernel_launch(void* const* d_in, const int* in_sizes, int n_in,
                              void* d_out, int out_size, void* d_ws, size_t ws_size,
                              hipStream_t stream) {
    const float* x     = (const float*)d_in[0];
    const void*  maskp = d_in[1];
    const float* W1    = (const float*)d_in[2];
    const float* b1    = (const float*)d_in[3];
    const float* gamma = (const float*)d_in[4];
    const float* beta  = (const float*)d_in[5];
    const float* W2    = (const float*)d_in[6];
    const float* b2    = (const float*)d_in[7];
    float* out = (float*)d_out;

    int* d_counts = (int*)d_ws;
    int* d_keff   = d_counts + 16;
    float* d_x2   = (float*)(d_counts + 32);
    float* d_base = d_x2 + BB * NN;
    float* d_fb   = d_base + (size_t)BB * NN * CC;
    int* d_idx    = (int*)(d_fb + (size_t)BB * NN * CC);
    float* d_xT   = (float*)d_out;   // free until k3

    hipLaunchKernelGGL(k0_counts, dim3(1), dim3(1024), 0, stream, maskp, d_counts, d_keff);
    hipLaunchKernelGGL(k1a_feats, dim3(BB * NN / 16), dim3(256), 0, stream,
                       x, W1, b1, d_base, d_fb);
    hipLaunchKernelGGL(k1b_xt, dim3(BB * NN / 16), dim3(256), 0, stream,
                       x, d_xT, d_x2);
    hipLaunchKernelGGL(k2_knn, dim3(BB * (NN / ROWS)), dim3(256), 0, stream,
                       x, d_xT, d_x2, d_counts, d_keff, d_idx);
    hipLaunchKernelGGL(k3_mlp, dim3(BB * NN / 16), dim3(256), 0, stream,
                       d_base, d_fb, d_idx, d_counts, gamma, beta, W2, b2, out);
}